// Round 1
// baseline (217.886 us; speedup 1.0000x reference)
//
#include <hip/hip_runtime.h>

#define NF   32
#define HGT  512
#define WID  512
#define BAT  8
#define HW   (HGT*WID)        // 262144
#define NPIX (BAT*HW)         // 2097152
#define NROWS (2*NPIX)        // 4194304
#define TPB  256
#define NBLK (NPIX/TPB)       // 8192

__device__ __forceinline__ float fast_tanh(float x) {
    // tanh(x) = 1 - 2/(exp(2x)+1); args here are |x| <~ 1.5 so no range issues
    float e = __expf(2.0f * x);
    return 1.0f - __fdividef(2.0f, e + 1.0f);
}

// Pass A: per-pixel g0 MLP, hrrp(center, up), hrrp(center, left)
__global__ __launch_bounds__(TPB) void kA(
    const float* __restrict__ c,
    const float* __restrict__ g0_w1, const float* __restrict__ g0_b1,
    const float* __restrict__ g0_w2, const float* __restrict__ g0_b2,
    const float* __restrict__ h_w1,  const float* __restrict__ h_b1,
    const float* __restrict__ h_w2,  const float* __restrict__ h_b2,
    float* __restrict__ G, float* __restrict__ WU, float* __restrict__ WL)
{
    int t = blockIdx.x * TPB + threadIdx.x;
    if (t >= NPIX) return;
    int b  = t >> 18;
    int hw = t & (HW - 1);
    int h  = hw >> 9;
    int w  = hw & 511;
    const float* c0 = c + (size_t)b * 2 * HW;   // c[b,0]
    float a  = c0[hw];
    float uu = c0[((h - 1) & 511) * WID + w];
    float ll = c0[h * WID + ((w - 1) & 511)];

    float g = g0_b2[0];
    #pragma unroll
    for (int k = 0; k < NF; ++k)
        g += fast_tanh(a * g0_w1[k] + g0_b1[k]) * g0_w2[k];

    float su = 0.f, sl = 0.f;
    #pragma unroll
    for (int k = 0; k < NF; ++k) {
        float w0 = h_w1[k], w1 = h_w1[NF + k], bb = h_b1[k], w2 = h_w2[k];
        su += (fast_tanh(a * w0 + uu * w1 + bb) + fast_tanh(uu * w0 + a * w1 + bb)) * w2;
        sl += (fast_tanh(a * w0 + ll * w1 + bb) + fast_tanh(ll * w0 + a * w1 + bb)) * w2;
    }
    G[t]  = g;
    WU[t] = 0.5f * su + h_b2[0];   // hrrp(c0[p], c0[up])
    WL[t] = 0.5f * sl + h_b2[0];   // hrrp(c0[p], c0[left])
}

// Pass B: err = c1 - (c0 + laplacian(G))
__global__ __launch_bounds__(TPB) void kB(
    const float* __restrict__ c, const float* __restrict__ G,
    float* __restrict__ ERR)
{
    int t = blockIdx.x * TPB + threadIdx.x;
    if (t >= NPIX) return;
    int b  = t >> 18;
    int hw = t & (HW - 1);
    int h  = hw >> 9;
    int w  = hw & 511;
    int hm = (h - 1) & 511, hp = (h + 1) & 511;
    int wm = (w - 1) & 511, wp = (w + 1) & 511;
    int b0 = b * HW;
    float lap = G[b0 + hm * WID + w] + G[b0 + hp * WID + w]
              + G[b0 + h * WID + wm] + G[b0 + h * WID + wp]
              - 4.0f * G[t];
    const float* cb = c + (size_t)b * 2 * HW;
    ERR[t] = cb[HW + hw] - (cb[hw] + lap);
}

// Pass C: two loss rows per pixel + block reduction -> partial[block]
__global__ __launch_bounds__(TPB) void kC(
    const float* __restrict__ WU, const float* __restrict__ WL,
    const float* __restrict__ ERR, float* __restrict__ partial)
{
    int t = blockIdx.x * TPB + threadIdx.x;
    int b  = t >> 18;
    int hw = t & (HW - 1);
    int h  = hw >> 9;
    int w  = hw & 511;
    int hm = (h - 1) & 511, hp = (h + 1) & 511;
    int wm = (w - 1) & 511, wp = (w + 1) & 511;
    int b0 = b * HW;
    int iUP = b0 + hm * WID + w;
    int iDN = b0 + hp * WID + w;
    int iLF = b0 + h * WID + wm;
    int iRT = b0 + h * WID + wp;
    int iUR = b0 + hm * WID + wp;
    int iDL = b0 + hp * WID + wm;

    float wu = WU[t], wl = WL[t];
    // omega_ii at p, up, left (all four symmetric hrrp neighbors each)
    float oii_p = wu + wl + WU[iDN] + WL[iRT];
    float oii_u = WU[iUP] + WL[iUP] + wu + WL[iUR];
    float oii_l = WU[iLF] + WL[iLF] + WU[iDL] + wl;

    float e = ERR[t], eu = ERR[iUP], el = ERR[iLF];

    // row i=0 (vertical pair): om0=oii_p, om3=oii_u, om1=om2=-wu
    float det0 = oii_p * oii_u - wu * wu;
    float l0 = det0 + (e * e * oii_u + eu * eu * oii_p + 2.0f * e * eu * wu) / det0;
    // row i=1 (horizontal pair): om3=oii_l, om1=om2=-wl
    float det1 = oii_p * oii_l - wl * wl;
    float l1 = det1 + (e * e * oii_l + el * el * oii_p + 2.0f * e * el * wl) / det1;

    float v = l0 + l1;
    // wave (64-lane) shuffle reduce
    #pragma unroll
    for (int off = 32; off > 0; off >>= 1)
        v += __shfl_down(v, off, 64);
    __shared__ float wsum[TPB / 64];
    int lane = threadIdx.x & 63, wave = threadIdx.x >> 6;
    if (lane == 0) wsum[wave] = v;
    __syncthreads();
    if (threadIdx.x == 0)
        partial[blockIdx.x] = wsum[0] + wsum[1] + wsum[2] + wsum[3];
}

// Pass D: deterministic final reduction of NBLK partials -> scalar out
__global__ __launch_bounds__(TPB) void kD(
    const float* __restrict__ partial, float* __restrict__ out)
{
    __shared__ double sm[TPB];
    double acc = 0.0;
    for (int i = threadIdx.x; i < NBLK; i += TPB)
        acc += (double)partial[i];
    sm[threadIdx.x] = acc;
    __syncthreads();
    #pragma unroll
    for (int s = TPB / 2; s > 0; s >>= 1) {
        if (threadIdx.x < s) sm[threadIdx.x] += sm[threadIdx.x + s];
        __syncthreads();
    }
    if (threadIdx.x == 0)
        out[0] = (float)(0.5 * sm[0] / (double)NROWS);
}

extern "C" void kernel_launch(void* const* d_in, const int* in_sizes, int n_in,
                              void* d_out, int out_size, void* d_ws, size_t ws_size,
                              hipStream_t stream) {
    const float* c     = (const float*)d_in[0];
    const float* g0_w1 = (const float*)d_in[1];
    const float* g0_b1 = (const float*)d_in[2];
    const float* g0_w2 = (const float*)d_in[3];
    const float* g0_b2 = (const float*)d_in[4];
    const float* h_w1  = (const float*)d_in[5];
    const float* h_b1  = (const float*)d_in[6];
    const float* h_w2  = (const float*)d_in[7];
    const float* h_b2  = (const float*)d_in[8];
    float* out = (float*)d_out;

    // ws layout: G | WU | WL | ERR | partial  (4*8MB + 32KB)
    float* ws  = (float*)d_ws;
    float* G   = ws;
    float* WU  = ws + (size_t)NPIX;
    float* WL  = ws + (size_t)2 * NPIX;
    float* ERR = ws + (size_t)3 * NPIX;
    float* PARTIAL = ws + (size_t)4 * NPIX;

    dim3 block(TPB), grid(NBLK);
    kA<<<grid, block, 0, stream>>>(c, g0_w1, g0_b1, g0_w2, g0_b2,
                                   h_w1, h_b1, h_w2, h_b2, G, WU, WL);
    kB<<<grid, block, 0, stream>>>(c, G, ERR);
    kC<<<grid, block, 0, stream>>>(WU, WL, ERR, PARTIAL);
    kD<<<1, block, 0, stream>>>(PARTIAL, out);
}

// Round 2
// 54.709 us; speedup vs baseline: 3.9826x; 3.9826x over previous
//
#include <hip/hip_runtime.h>

#define NF   32
#define HGT  512
#define WID  512
#define BAT  8
#define HW   (HGT*WID)        // 262144
#define NPIX (BAT*HW)         // 2097152
#define NROWS (2*NPIX)        // 4194304
#define TPB  256
#define NBLK (NPIX/TPB)       // 8192

#define NT   64               // hrrp table is NT x NT over [0,1]^2
#define NG   1024             // g0 table size over [0,1]
#define ABLK 2048             // grid-stride blocks for kA2

__device__ __forceinline__ float fast_tanh(float x) {
    float e = __expf(2.0f * x);
    return 1.0f - __fdividef(2.0f, e + 1.0f);
}

// Table builder: TH[iy*NT+ix] = hrrp(x,y), TG[i] = g0(x)
__global__ __launch_bounds__(TPB) void kT(
    const float* __restrict__ g0_w1, const float* __restrict__ g0_b1,
    const float* __restrict__ g0_w2, const float* __restrict__ g0_b2,
    const float* __restrict__ h_w1,  const float* __restrict__ h_b1,
    const float* __restrict__ h_w2,  const float* __restrict__ h_b2,
    float* __restrict__ TH, float* __restrict__ TG)
{
    int t = blockIdx.x * TPB + threadIdx.x;
    if (t < NT * NT) {
        int iy = t >> 6, ix = t & (NT - 1);
        float x = ix * (1.0f / (NT - 1));
        float y = iy * (1.0f / (NT - 1));
        float s = 0.f;
        #pragma unroll
        for (int k = 0; k < NF; ++k) {
            float w0 = h_w1[k], w1 = h_w1[NF + k], bb = h_b1[k], w2 = h_w2[k];
            s += (fast_tanh(x * w0 + y * w1 + bb) + fast_tanh(y * w0 + x * w1 + bb)) * w2;
        }
        TH[t] = 0.5f * s + h_b2[0];
    } else if (t < NT * NT + NG) {
        int i = t - NT * NT;
        float x = i * (1.0f / (NG - 1));
        float g = g0_b2[0];
        #pragma unroll
        for (int k = 0; k < NF; ++k)
            g += fast_tanh(x * g0_w1[k] + g0_b1[k]) * g0_w2[k];
        TG[i] = g;
    }
}

__device__ __forceinline__ float bilin(const float* __restrict__ th, float x, float y) {
    float fx = x * (float)(NT - 1), fy = y * (float)(NT - 1);
    float bx = floorf(fx), by = floorf(fy);
    int ix = (int)bx, iy = (int)by;
    fx -= bx; fy -= by;
    int base = iy * NT + ix;
    float v00 = th[base], v01 = th[base + 1];
    float v10 = th[base + NT], v11 = th[base + NT + 1];
    float a0 = v00 + fx * (v01 - v00);
    float a1 = v10 + fx * (v11 - v10);
    return a0 + fy * (a1 - a0);
}

__device__ __forceinline__ float lerp1(const float* __restrict__ tg, float x) {
    float f = x * (float)(NG - 1);
    float b = floorf(f);
    int i = (int)b;
    f -= b;
    float v0 = tg[i], v1 = tg[i + 1];
    return v0 + f * (v1 - v0);
}

// Pass A (table version): per-pixel g0, hrrp(center,up), hrrp(center,left)
__global__ __launch_bounds__(TPB) void kA2(
    const float* __restrict__ c,
    const float* __restrict__ THg, const float* __restrict__ TGg,
    float* __restrict__ G, float* __restrict__ WU, float* __restrict__ WL)
{
    __shared__ float sTH[NT * NT];
    __shared__ float sTG[NG];
    for (int i = threadIdx.x; i < NT * NT; i += TPB) sTH[i] = THg[i];
    for (int i = threadIdx.x; i < NG; i += TPB) sTG[i] = TGg[i];
    __syncthreads();

    for (int t = blockIdx.x * TPB + threadIdx.x; t < NPIX; t += ABLK * TPB) {
        int b  = t >> 18;
        int hw = t & (HW - 1);
        int h  = hw >> 9;
        int w  = hw & 511;
        const float* c0 = c + (size_t)b * 2 * HW;
        float a  = c0[hw];
        float uu = c0[((h - 1) & 511) * WID + w];
        float ll = c0[h * WID + ((w - 1) & 511)];
        G[t]  = lerp1(sTG, a);
        WU[t] = bilin(sTH, a, uu);
        WL[t] = bilin(sTH, a, ll);
    }
}

// Pass B: err = c1 - (c0 + laplacian(G))
__global__ __launch_bounds__(TPB) void kB(
    const float* __restrict__ c, const float* __restrict__ G,
    float* __restrict__ ERR)
{
    int t = blockIdx.x * TPB + threadIdx.x;
    if (t >= NPIX) return;
    int b  = t >> 18;
    int hw = t & (HW - 1);
    int h  = hw >> 9;
    int w  = hw & 511;
    int hm = (h - 1) & 511, hp = (h + 1) & 511;
    int wm = (w - 1) & 511, wp = (w + 1) & 511;
    int b0 = b * HW;
    float lap = G[b0 + hm * WID + w] + G[b0 + hp * WID + w]
              + G[b0 + h * WID + wm] + G[b0 + h * WID + wp]
              - 4.0f * G[t];
    const float* cb = c + (size_t)b * 2 * HW;
    ERR[t] = cb[HW + hw] - (cb[hw] + lap);
}

// Pass C: two loss rows per pixel + block reduction -> partial[block]
__global__ __launch_bounds__(TPB) void kC(
    const float* __restrict__ WU, const float* __restrict__ WL,
    const float* __restrict__ ERR, float* __restrict__ partial)
{
    int t = blockIdx.x * TPB + threadIdx.x;
    int b  = t >> 18;
    int hw = t & (HW - 1);
    int h  = hw >> 9;
    int w  = hw & 511;
    int hm = (h - 1) & 511, hp = (h + 1) & 511;
    int wm = (w - 1) & 511, wp = (w + 1) & 511;
    int b0 = b * HW;
    int iUP = b0 + hm * WID + w;
    int iDN = b0 + hp * WID + w;
    int iLF = b0 + h * WID + wm;
    int iRT = b0 + h * WID + wp;
    int iUR = b0 + hm * WID + wp;
    int iDL = b0 + hp * WID + wm;

    float wu = WU[t], wl = WL[t];
    float oii_p = wu + wl + WU[iDN] + WL[iRT];
    float oii_u = WU[iUP] + WL[iUP] + wu + WL[iUR];
    float oii_l = WU[iLF] + WL[iLF] + WU[iDL] + wl;

    float e = ERR[t], eu = ERR[iUP], el = ERR[iLF];

    float det0 = oii_p * oii_u - wu * wu;
    float l0 = det0 + (e * e * oii_u + eu * eu * oii_p + 2.0f * e * eu * wu) / det0;
    float det1 = oii_p * oii_l - wl * wl;
    float l1 = det1 + (e * e * oii_l + el * el * oii_p + 2.0f * e * el * wl) / det1;

    float v = l0 + l1;
    #pragma unroll
    for (int off = 32; off > 0; off >>= 1)
        v += __shfl_down(v, off, 64);
    __shared__ float wsum[TPB / 64];
    int lane = threadIdx.x & 63, wave = threadIdx.x >> 6;
    if (lane == 0) wsum[wave] = v;
    __syncthreads();
    if (threadIdx.x == 0)
        partial[blockIdx.x] = wsum[0] + wsum[1] + wsum[2] + wsum[3];
}

// Pass D: deterministic final reduction
__global__ __launch_bounds__(TPB) void kD(
    const float* __restrict__ partial, float* __restrict__ out)
{
    __shared__ double sm[TPB];
    double acc = 0.0;
    for (int i = threadIdx.x; i < NBLK; i += TPB)
        acc += (double)partial[i];
    sm[threadIdx.x] = acc;
    __syncthreads();
    #pragma unroll
    for (int s = TPB / 2; s > 0; s >>= 1) {
        if (threadIdx.x < s) sm[threadIdx.x] += sm[threadIdx.x + s];
        __syncthreads();
    }
    if (threadIdx.x == 0)
        out[0] = (float)(0.5 * sm[0] / (double)NROWS);
}

extern "C" void kernel_launch(void* const* d_in, const int* in_sizes, int n_in,
                              void* d_out, int out_size, void* d_ws, size_t ws_size,
                              hipStream_t stream) {
    const float* c     = (const float*)d_in[0];
    const float* g0_w1 = (const float*)d_in[1];
    const float* g0_b1 = (const float*)d_in[2];
    const float* g0_w2 = (const float*)d_in[3];
    const float* g0_b2 = (const float*)d_in[4];
    const float* h_w1  = (const float*)d_in[5];
    const float* h_b1  = (const float*)d_in[6];
    const float* h_w2  = (const float*)d_in[7];
    const float* h_b2  = (const float*)d_in[8];
    float* out = (float*)d_out;

    // ws layout: G | WU | WL | ERR | partial | TH | TG
    float* ws  = (float*)d_ws;
    float* G   = ws;
    float* WU  = ws + (size_t)NPIX;
    float* WL  = ws + (size_t)2 * NPIX;
    float* ERR = ws + (size_t)3 * NPIX;
    float* PARTIAL = ws + (size_t)4 * NPIX;
    float* TH  = PARTIAL + NBLK;
    float* TG  = TH + NT * NT;

    dim3 block(TPB);
    kT<<<dim3((NT * NT + NG + TPB - 1) / TPB), block, 0, stream>>>(
        g0_w1, g0_b1, g0_w2, g0_b2, h_w1, h_b1, h_w2, h_b2, TH, TG);
    kA2<<<dim3(ABLK), block, 0, stream>>>(c, TH, TG, G, WU, WL);
    kB<<<dim3(NBLK), block, 0, stream>>>(c, G, ERR);
    kC<<<dim3(NBLK), block, 0, stream>>>(WU, WL, ERR, PARTIAL);
    kD<<<1, block, 0, stream>>>(PARTIAL, out);
}

// Round 3
// 34.387 us; speedup vs baseline: 6.3363x; 1.5910x over previous
//
#include <hip/hip_runtime.h>

#define NF   32
#define HGT  512
#define WID  512
#define BAT  8
#define HW   (HGT*WID)        // 262144
#define NPIX (BAT*HW)         // 2097152
#define NROWS (2*NPIX)        // 4194304
#define TPB  256

#define NT   40               // hrrp table NT x NT over [0,1]^2 (err ~2e-6)
#define NG   256              // g0 table over [0,1] (err ~2e-7)

#define TY   32               // tile height
#define TX   64               // tile width
#define NTILE (NPIX/(TY*TX))  // 1024 blocks

// LDS region sizes
#define C0H  (TY+3)           // 35
#define C0W  (TX+3)           // 67
#define WH   (TY+2)           // 34
#define WW   (TX+2)           // 66
#define EH   (TY+1)           // 33
#define EW   (TX+1)           // 65

__device__ __forceinline__ float fast_tanh(float x) {
    float e = __expf(2.0f * x);
    return 1.0f - __fdividef(2.0f, e + 1.0f);
}

// Table builder: TH[iy*NT+ix] = hrrp(x,y), TG[i] = g0(x)
__global__ __launch_bounds__(TPB) void kT(
    const float* __restrict__ g0_w1, const float* __restrict__ g0_b1,
    const float* __restrict__ g0_w2, const float* __restrict__ g0_b2,
    const float* __restrict__ h_w1,  const float* __restrict__ h_b1,
    const float* __restrict__ h_w2,  const float* __restrict__ h_b2,
    float* __restrict__ TH, float* __restrict__ TG)
{
    int t = blockIdx.x * TPB + threadIdx.x;
    if (t < NT * NT) {
        int iy = t / NT, ix = t - iy * NT;
        float x = ix * (1.0f / (NT - 1));
        float y = iy * (1.0f / (NT - 1));
        float s = 0.f;
        #pragma unroll
        for (int k = 0; k < NF; ++k) {
            float w0 = h_w1[k], w1 = h_w1[NF + k], bb = h_b1[k], w2 = h_w2[k];
            s += (fast_tanh(x * w0 + y * w1 + bb) + fast_tanh(y * w0 + x * w1 + bb)) * w2;
        }
        TH[t] = 0.5f * s + h_b2[0];
    } else if (t < NT * NT + NG) {
        int i = t - NT * NT;
        float x = i * (1.0f / (NG - 1));
        float g = g0_b2[0];
        #pragma unroll
        for (int k = 0; k < NF; ++k)
            g += fast_tanh(x * g0_w1[k] + g0_b1[k]) * g0_w2[k];
        TG[i] = g;
    }
}

__device__ __forceinline__ float bilin(const float* __restrict__ th, float x, float y) {
    float fx = x * (float)(NT - 1), fy = y * (float)(NT - 1);
    float bx = floorf(fx), by = floorf(fy);
    int ix = (int)bx, iy = (int)by;
    fx -= bx; fy -= by;
    int base = iy * NT + ix;
    float v00 = th[base], v01 = th[base + 1];
    float v10 = th[base + NT], v11 = th[base + NT + 1];
    float a0 = v00 + fx * (v01 - v00);
    float a1 = v10 + fx * (v11 - v10);
    return a0 + fy * (a1 - a0);
}

__device__ __forceinline__ float lerp1(const float* __restrict__ tg, float x) {
    float f = x * (float)(NG - 1);
    float b = floorf(f);
    int i = (int)b;
    f -= b;
    float v0 = tg[i], v1 = tg[i + 1];
    return v0 + f * (v1 - v0);
}

// Fused: stage c0 tile+halo -> G -> WU/WL -> ERR -> loss -> block partial
__global__ __launch_bounds__(TPB) void kF(
    const float* __restrict__ c, const float* __restrict__ THg,
    const float* __restrict__ TGg, float* __restrict__ partial)
{
    __shared__ float sTH[NT * NT];
    __shared__ float sTG[NG];
    __shared__ float sC0[C0H * C0W];
    __shared__ float sG [C0H * C0W];
    __shared__ float sWU[WH * WW];
    __shared__ float sWL[WH * WW];
    __shared__ float sERR[EH * EW];
    __shared__ float wsum[TPB / 64];

    int tid = threadIdx.x;
    int bid = blockIdx.x;
    int b   = bid >> 7;              // 128 tiles per batch image
    int rem = bid & 127;
    int Y0  = (rem >> 3) << 5;       // 16 tiles vertically * 32
    int X0  = (rem & 7) << 6;        // 8 tiles horizontally * 64
    const float* c0g = c + (size_t)b * 2 * HW;
    const float* c1g = c0g + HW;

    for (int i = tid; i < NT * NT; i += TPB) sTH[i] = THg[i];
    for (int i = tid; i < NG; i += TPB)      sTG[i] = TGg[i];
    // stage c0 (35 x 67, wrap-indexed)
    for (int i = tid; i < C0H * C0W; i += TPB) {
        int y = i / C0W, x = i - y * C0W;
        int gy = (Y0 + y - 2) & 511, gx = (X0 + x - 2) & 511;
        sC0[i] = c0g[(gy << 9) + gx];
    }
    __syncthreads();

    // G over 35x67 ; W over 34x66 (no cross-dependency, one sync after both)
    for (int i = tid; i < C0H * C0W; i += TPB)
        sG[i] = lerp1(sTG, sC0[i]);
    for (int i = tid; i < WH * WW; i += TPB) {
        int y = i / WW, x = i - y * WW;
        float a  = sC0[(y + 1) * C0W + (x + 1)];
        float uu = sC0[ y      * C0W + (x + 1)];
        float ll = sC0[(y + 1) * C0W +  x     ];
        sWU[i] = bilin(sTH, a, uu);
        sWL[i] = bilin(sTH, a, ll);
    }
    __syncthreads();

    // ERR over 33x65
    for (int i = tid; i < EH * EW; i += TPB) {
        int y = i / EW, x = i - y * EW;
        int gy = (Y0 + y - 1) & 511, gx = (X0 + x - 1) & 511;
        int ci = (y + 1) * C0W + (x + 1);
        float lap = sG[ci - C0W] + sG[ci + C0W] + sG[ci - 1] + sG[ci + 1]
                  - 4.0f * sG[ci];
        sERR[i] = c1g[(gy << 9) + gx] - sC0[ci] - lap;
    }
    __syncthreads();

    // loss: each thread 8 pixels (rows ty0, ty0+4, ..., ty0+28)
    float acc = 0.f;
    int tx = tid & 63, ty0 = tid >> 6;
    #pragma unroll
    for (int r = 0; r < 8; ++r) {
        int y = ty0 + (r << 2);
        int x = tx;
        int wp = (y + 1) * WW + (x + 1);
        float wu = sWU[wp], wl = sWL[wp];
        float oii_p = wu + wl + sWU[wp + WW] + sWL[wp + 1];
        float oii_u = sWU[wp - WW] + sWL[wp - WW] + wu + sWL[wp - WW + 1];
        float oii_l = sWU[wp - 1] + sWL[wp - 1] + sWU[wp + WW - 1] + wl;
        int ep = (y + 1) * EW + (x + 1);
        float e = sERR[ep], eu = sERR[ep - EW], el = sERR[ep - 1];
        float det0 = oii_p * oii_u - wu * wu;
        float l0 = det0 + __fdividef(e * e * oii_u + eu * eu * oii_p + 2.0f * e * eu * wu, det0);
        float det1 = oii_p * oii_l - wl * wl;
        float l1 = det1 + __fdividef(e * e * oii_l + el * el * oii_p + 2.0f * e * el * wl, det1);
        acc += l0 + l1;
    }
    #pragma unroll
    for (int off = 32; off > 0; off >>= 1)
        acc += __shfl_down(acc, off, 64);
    if ((tid & 63) == 0) wsum[tid >> 6] = acc;
    __syncthreads();
    if (tid == 0)
        partial[bid] = wsum[0] + wsum[1] + wsum[2] + wsum[3];
}

// Deterministic final reduction of NTILE partials
__global__ __launch_bounds__(TPB) void kD(
    const float* __restrict__ partial, float* __restrict__ out)
{
    __shared__ double sm[TPB];
    double acc = 0.0;
    for (int i = threadIdx.x; i < NTILE; i += TPB)
        acc += (double)partial[i];
    sm[threadIdx.x] = acc;
    __syncthreads();
    #pragma unroll
    for (int s = TPB / 2; s > 0; s >>= 1) {
        if (threadIdx.x < s) sm[threadIdx.x] += sm[threadIdx.x + s];
        __syncthreads();
    }
    if (threadIdx.x == 0)
        out[0] = (float)(0.5 * sm[0] / (double)NROWS);
}

extern "C" void kernel_launch(void* const* d_in, const int* in_sizes, int n_in,
                              void* d_out, int out_size, void* d_ws, size_t ws_size,
                              hipStream_t stream) {
    const float* c     = (const float*)d_in[0];
    const float* g0_w1 = (const float*)d_in[1];
    const float* g0_b1 = (const float*)d_in[2];
    const float* g0_w2 = (const float*)d_in[3];
    const float* g0_b2 = (const float*)d_in[4];
    const float* h_w1  = (const float*)d_in[5];
    const float* h_b1  = (const float*)d_in[6];
    const float* h_w2  = (const float*)d_in[7];
    const float* h_b2  = (const float*)d_in[8];
    float* out = (float*)d_out;

    // ws layout: TH | TG | partial
    float* ws = (float*)d_ws;
    float* TH = ws;
    float* TG = TH + NT * NT;
    float* PARTIAL = TG + NG;

    dim3 block(TPB);
    kT<<<dim3((NT * NT + NG + TPB - 1) / TPB), block, 0, stream>>>(
        g0_w1, g0_b1, g0_w2, g0_b2, h_w1, h_b1, h_w2, h_b2, TH, TG);
    kF<<<dim3(NTILE), block, 0, stream>>>(c, TH, TG, PARTIAL);
    kD<<<1, block, 0, stream>>>(PARTIAL, out);
}

// Round 4
// 34.255 us; speedup vs baseline: 6.3608x; 1.0039x over previous
//
#include <hip/hip_runtime.h>
#include <math.h>

#define NF   32
#define HGT  512
#define WID  512
#define BAT  8
#define HW   (HGT*WID)        // 262144
#define NPIX (BAT*HW)         // 2097152
#define NROWS (2*NPIX)        // 4194304
#define TPB  256

#define TY   32               // tile height
#define TX   64               // tile width
#define NTILE (NPIX/(TY*TX))  // 1024 blocks

#define NC   7                // hrrp Chebyshev: degree 6, 7x7 coeffs
#define NCG  8                // g0 Chebyshev: degree 7, 8 coeffs

#define STR  68               // LDS row stride (words)

__device__ __forceinline__ float fast_tanh(float x) {
    float e = __expf(2.0f * x);
    return 1.0f - __fdividef(2.0f, e + 1.0f);
}

// ---------------- kT: build Chebyshev coefficients ----------------
// CH[p*7+q]: 2D cheb coeffs of hrrp(x,y) on [0,1]^2 (includes 0-index halving)
// CG[p]:     1D cheb coeffs of g0(x) on [0,1]
__global__ __launch_bounds__(128) void kT(
    const float* __restrict__ g0_w1, const float* __restrict__ g0_b1,
    const float* __restrict__ g0_w2, const float* __restrict__ g0_b2,
    const float* __restrict__ h_w1,  const float* __restrict__ h_b1,
    const float* __restrict__ h_w2,  const float* __restrict__ h_b2,
    float* __restrict__ CH, float* __restrict__ CG)
{
    __shared__ float cp[NC * NC];    // cos(p*pi*(i+0.5)/7)
    __shared__ float cg8[NCG * NCG]; // cos(p*pi*(i+0.5)/8)
    __shared__ float F[NC * NC];
    __shared__ float Fg[NCG];
    int t = threadIdx.x;
    if (t < NC * NC) {
        int p = t / NC, i = t - NC * p;
        cp[t] = cosf((float)M_PI * (float)p * ((float)i + 0.5f) / (float)NC);
    } else if (t < NC * NC + NCG * NCG) {
        int u = t - NC * NC;
        int p = u / NCG, i = u - NCG * p;
        cg8[u] = cosf((float)M_PI * (float)p * ((float)i + 0.5f) / (float)NCG);
    }
    __syncthreads();
    if (t < NC * NC) {
        int i = t / NC, j = t - NC * i;
        float x = 0.5f * (cp[NC + i] + 1.0f);   // node_i
        float y = 0.5f * (cp[NC + j] + 1.0f);
        float s = 0.f;
        #pragma unroll
        for (int k = 0; k < NF; ++k) {
            float w0 = h_w1[k], w1 = h_w1[NF + k], bb = h_b1[k], w2 = h_w2[k];
            s += (fast_tanh(x * w0 + y * w1 + bb) + fast_tanh(y * w0 + x * w1 + bb)) * w2;
        }
        F[t] = 0.5f * s + h_b2[0];
    } else if (t < NC * NC + NCG) {
        int i = t - NC * NC;
        float x = 0.5f * (cg8[NCG + i] + 1.0f);
        float g = g0_b2[0];
        #pragma unroll
        for (int k = 0; k < NF; ++k)
            g += fast_tanh(x * g0_w1[k] + g0_b1[k]) * g0_w2[k];
        Fg[i] = g;
    }
    __syncthreads();
    if (t < NC * NC) {
        int p = t / NC, q = t - NC * p;
        float sum = 0.f;
        #pragma unroll
        for (int i = 0; i < NC; ++i)
            #pragma unroll
            for (int j = 0; j < NC; ++j)
                sum += F[i * NC + j] * cp[p * NC + i] * cp[q * NC + j];
        float kp = p ? 1.0f : 0.5f, kq = q ? 1.0f : 0.5f;
        CH[t] = (4.0f / (float)(NC * NC)) * kp * kq * sum;
    } else if (t < NC * NC + NCG) {
        int p = t - NC * NC;
        float sum = 0.f;
        #pragma unroll
        for (int i = 0; i < NCG; ++i)
            sum += Fg[i] * cg8[p * NCG + i];
        CG[p] = (2.0f / (float)NCG) * (p ? 1.0f : 0.5f) * sum;
    }
}

// ---------------- kF: fused tile kernel ----------------
__global__ __launch_bounds__(TPB) void kF(
    const float* __restrict__ c, const float* __restrict__ CHg,
    const float* __restrict__ CGg, float* __restrict__ partial)
{
    __shared__ float sC0[35 * STR];
    __shared__ float sG [35 * STR];
    __shared__ float sWU[34 * STR];
    __shared__ float sWL[34 * STR];
    __shared__ float sERR[33 * STR];
    __shared__ float wsum[TPB / 64];

    float CH[NC * NC], CG[NCG];
    #pragma unroll
    for (int i = 0; i < NC * NC; ++i) CH[i] = CHg[i];
    #pragma unroll
    for (int i = 0; i < NCG; ++i) CG[i] = CGg[i];

    int tid = threadIdx.x;
    int bid = blockIdx.x;
    int b   = bid >> 7;              // 128 tiles per batch image
    int rem = bid & 127;
    int Y0  = (rem >> 3) << 5;       // 16 tiles vertically * 32
    int X0  = (rem & 7) << 6;        // 8 tiles horizontally * 64
    const float* c0g = c + (size_t)b * 2 * HW;
    const float* c1g = c0g + HW;

    // --- stage c0 (35x67, wrap) and compute G = cheb(c0) in the same pass
    for (int i = tid; i < 35 * 67; i += TPB) {
        int y = i / 67, x = i - 67 * y;
        int gy = (Y0 + y - 2) & 511, gx = (X0 + x - 2) & 511;
        float v = c0g[(gy << 9) + gx];
        sC0[y * STR + x] = v;
        float tt = 2.0f * v - 1.0f;
        float t0 = 1.0f, t1 = tt;
        float g = CG[0] + CG[1] * tt;
        #pragma unroll
        for (int p = 2; p < NCG; ++p) {
            float t2 = 2.0f * tt * t1 - t0;
            g += CG[p] * t2;
            t0 = t1; t1 = t2;
        }
        sG[y * STR + x] = g;
    }
    __syncthreads();

    // --- W: hrrp(center, up) and hrrp(center, left) via shared s_q(a)
    for (int i = tid; i < 34 * 66; i += TPB) {
        int y = i / 66, x = i - 66 * y;
        float a  = sC0[(y + 1) * STR + x + 1];
        float uu = sC0[ y      * STR + x + 1];
        float ll = sC0[(y + 1) * STR + x    ];

        float ta = 2.0f * a - 1.0f;
        float T[NC];
        T[0] = 1.0f; T[1] = ta;
        #pragma unroll
        for (int p = 2; p < NC; ++p) T[p] = 2.0f * ta * T[p - 1] - T[p - 2];
        float s[NC];
        #pragma unroll
        for (int q = 0; q < NC; ++q) {
            float acc = CH[q];                  // p=0, T[0]=1
            #pragma unroll
            for (int p = 1; p < NC; ++p) acc += CH[p * NC + q] * T[p];
            s[q] = acc;
        }
        float tu = 2.0f * uu - 1.0f;
        float u0 = 1.0f, u1 = tu;
        float wu = s[0] + s[1] * tu;
        #pragma unroll
        for (int q = 2; q < NC; ++q) {
            float u2 = 2.0f * tu * u1 - u0;
            wu += s[q] * u2;
            u0 = u1; u1 = u2;
        }
        float tl = 2.0f * ll - 1.0f;
        float l0 = 1.0f, l1 = tl;
        float wl = s[0] + s[1] * tl;
        #pragma unroll
        for (int q = 2; q < NC; ++q) {
            float l2 = 2.0f * tl * l1 - l0;
            wl += s[q] * l2;
            l0 = l1; l1 = l2;
        }
        sWU[y * STR + x] = wu;
        sWL[y * STR + x] = wl;
    }
    __syncthreads();

    // --- ERR over 33x65
    for (int i = tid; i < 33 * 65; i += TPB) {
        int y = i / 65, x = i - 65 * y;
        int ci = (y + 1) * STR + (x + 1);
        float lap = sG[ci - STR] + sG[ci + STR] + sG[ci - 1] + sG[ci + 1]
                  - 4.0f * sG[ci];
        int gy = (Y0 + y - 1) & 511, gx = (X0 + x - 1) & 511;
        sERR[y * STR + x] = c1g[(gy << 9) + gx] - sC0[ci] - lap;
    }
    __syncthreads();

    // --- loss: each thread 8 pixels
    float acc = 0.f;
    int tx = tid & 63, ty0 = tid >> 6;
    #pragma unroll
    for (int r = 0; r < 8; ++r) {
        int y = ty0 + (r << 2);
        int x = tx;
        int wp = (y + 1) * STR + (x + 1);
        float wu = sWU[wp], wl = sWL[wp];
        float oii_p = wu + wl + sWU[wp + STR] + sWL[wp + 1];
        float oii_u = sWU[wp - STR] + sWL[wp - STR] + wu + sWL[wp - STR + 1];
        float oii_l = sWU[wp - 1] + sWL[wp - 1] + sWU[wp + STR - 1] + wl;
        int ep = (y + 1) * STR + (x + 1);
        float e = sERR[ep], eu = sERR[ep - STR], el = sERR[ep - 1];
        float det0 = oii_p * oii_u - wu * wu;
        float l0 = det0 + __fdividef(e * e * oii_u + eu * eu * oii_p + 2.0f * e * eu * wu, det0);
        float det1 = oii_p * oii_l - wl * wl;
        float l1 = det1 + __fdividef(e * e * oii_l + el * el * oii_p + 2.0f * e * el * wl, det1);
        acc += l0 + l1;
    }
    #pragma unroll
    for (int off = 32; off > 0; off >>= 1)
        acc += __shfl_down(acc, off, 64);
    if ((tid & 63) == 0) wsum[tid >> 6] = acc;
    __syncthreads();
    if (tid == 0)
        partial[bid] = wsum[0] + wsum[1] + wsum[2] + wsum[3];
}

// ---------------- kD: deterministic final reduction ----------------
__global__ __launch_bounds__(TPB) void kD(
    const float* __restrict__ partial, float* __restrict__ out)
{
    __shared__ double sm[TPB];
    double acc = 0.0;
    for (int i = threadIdx.x; i < NTILE; i += TPB)
        acc += (double)partial[i];
    sm[threadIdx.x] = acc;
    __syncthreads();
    #pragma unroll
    for (int s = TPB / 2; s > 0; s >>= 1) {
        if (threadIdx.x < s) sm[threadIdx.x] += sm[threadIdx.x + s];
        __syncthreads();
    }
    if (threadIdx.x == 0)
        out[0] = (float)(0.5 * sm[0] / (double)NROWS);
}

extern "C" void kernel_launch(void* const* d_in, const int* in_sizes, int n_in,
                              void* d_out, int out_size, void* d_ws, size_t ws_size,
                              hipStream_t stream) {
    const float* c     = (const float*)d_in[0];
    const float* g0_w1 = (const float*)d_in[1];
    const float* g0_b1 = (const float*)d_in[2];
    const float* g0_w2 = (const float*)d_in[3];
    const float* g0_b2 = (const float*)d_in[4];
    const float* h_w1  = (const float*)d_in[5];
    const float* h_b1  = (const float*)d_in[6];
    const float* h_w2  = (const float*)d_in[7];
    const float* h_b2  = (const float*)d_in[8];
    float* out = (float*)d_out;

    // ws layout: CH | CG | partial
    float* ws = (float*)d_ws;
    float* CH = ws;
    float* CG = CH + NC * NC;
    float* PARTIAL = CG + NCG;

    kT<<<dim3(1), dim3(128), 0, stream>>>(
        g0_w1, g0_b1, g0_w2, g0_b2, h_w1, h_b1, h_w2, h_b2, CH, CG);
    kF<<<dim3(NTILE), dim3(TPB), 0, stream>>>(c, CH, CG, PARTIAL);
    kD<<<1, dim3(TPB), 0, stream>>>(PARTIAL, out);
}